// Round 3
// baseline (16103.450 us; speedup 1.0000x reference)
//
#include <hip/hip_runtime.h>
#include <hip/hip_bf16.h>

// LSTM: B=64, S=1024, I=256, H=512, 2 layers. Inputs fp32, outputs fp32.
// Persistent kernel, 128 WGs (64/layer), layer-1 pipelined 1 step behind layer-0.
// Per-WG: 8 h-columns x 4 gates (32 gate cols), weights converted fp32->bf16
// once into VGPRs, h exchanged (bf16) through global ping-pong buffers with
// device-scope release/acquire flags. Cell state c kept in fp32 registers.

#define BB 64
#define SS 1024
#define HH 512
#define NWG 64   // WGs per layer

typedef unsigned short u16;
typedef __attribute__((ext_vector_type(8))) short bf16x8;
typedef __attribute__((ext_vector_type(4))) float f32x4;

__device__ __forceinline__ bf16x8 ldfrag(const u16* p) {
  return *reinterpret_cast<const bf16x8*>(p);
}
__device__ __forceinline__ u16 f2bf(float f) {
  __hip_bfloat16 h = __float2bfloat16(f);
  return *reinterpret_cast<u16*>(&h);
}
// convert 8 contiguous fp32 -> bf16x8 fragment (two vectorized 16B loads)
__device__ __forceinline__ bf16x8 cvt8(const float* p) {
  const f32x4* v = reinterpret_cast<const f32x4*>(p);
  f32x4 a = v[0], b = v[1];
  bf16x8 r;
  r[0] = (short)f2bf(a[0]); r[1] = (short)f2bf(a[1]);
  r[2] = (short)f2bf(a[2]); r[3] = (short)f2bf(a[3]);
  r[4] = (short)f2bf(b[0]); r[5] = (short)f2bf(b[1]);
  r[6] = (short)f2bf(b[2]); r[7] = (short)f2bf(b[3]);
  return r;
}
__device__ __forceinline__ float sigm(float x) { return 1.0f / (1.0f + __expf(-x)); }
__device__ __forceinline__ float tanh_f(float x) { return 2.0f / (1.0f + __expf(-2.0f * x)) - 1.0f; }

template<int KIN, int LAYER, bool XF32>
__device__ __forceinline__ void run_layer(
    const void* __restrict__ xin,  // (B,S,KIN): fp32 if XF32 else bf16
    const float* __restrict__ Wih, // (2048, KIN) fp32
    const float* __restrict__ Whh, // (2048, 512) fp32
    const float* __restrict__ bih, // (2048) fp32
    const float* __restrict__ bhh, // (2048) fp32
    float* __restrict__ outF,      // layer1: (B,S,512) fp32 out1; layer0: null
    u16*   __restrict__ outB,      // layer0: (B,S,512) bf16 out0; layer1: null
    float* __restrict__ hn,        // (B,512) fp32 h_n slice
    float* __restrict__ cn,        // (B,512) fp32 c_n slice
    u16* __restrict__ hbuf,        // 2*B*512 bf16 ping-pong (zeroed)
    int* flag_own,                 // [S] arrival counters (zeroed)
    int* flag_dep)                 // [S] producer-layer counters (layer 1 only)
{
  const int g    = blockIdx.x & (NWG - 1);
  const int g8   = g * 8;
  const int tid  = threadIdx.x;
  const int wv   = tid >> 6;     // batch tile 0..3
  const int lane = tid & 63;
  const int q    = lane >> 4;    // quad
  const int n16  = lane & 15;    // column-in-tile

  // gate-column mapping: col c (0..31): gate = c>>3, jj = c&7
  const int c0 = n16;            // cols 0..15  (i, f)
  const int c1 = 16 + n16;       // cols 16..31 (g, o)
  const int wrow0 = ((c0 >> 3) * HH) + g8 + (c0 & 7);
  const int wrow1 = ((c1 >> 3) * HH) + g8 + (c1 & 7);

  // ---- preload weight fragments, converting fp32 -> bf16 (once) ----
  bf16x8 wihA[KIN / 32], wihB[KIN / 32], whhA[16], whhB[16];
#pragma unroll
  for (int ks = 0; ks < KIN / 32; ++ks) {
    wihA[ks] = cvt8(Wih + (size_t)wrow0 * KIN + ks * 32 + q * 8);
    wihB[ks] = cvt8(Wih + (size_t)wrow1 * KIN + ks * 32 + q * 8);
  }
#pragma unroll
  for (int ks = 0; ks < 16; ++ks) {
    whhA[ks] = cvt8(Whh + (size_t)wrow0 * HH + ks * 32 + q * 8);
    whhB[ks] = cvt8(Whh + (size_t)wrow1 * HH + ks * 32 + q * 8);
  }
  const float bias0 = bih[wrow0] + bhh[wrow0];
  const float bias1 = bih[wrow1] + bhh[wrow1];

  float cst[4] = {0.f, 0.f, 0.f, 0.f};   // fp32 cell state (lanes n16<8)

  const int arow = wv * 16 + n16;        // batch row this lane loads for A-frags

  for (int t = 0; t < SS; ++t) {
    // ---- wait for h_t (own layer) and producer out0[:,t,:] (layer 1) ----
    if (tid == 0) {
      if (t > 0) {
        while (__hip_atomic_load(&flag_own[t - 1], __ATOMIC_RELAXED,
                                 __HIP_MEMORY_SCOPE_AGENT) < NWG)
          __builtin_amdgcn_s_sleep(1);
      }
      if (LAYER == 1) {
        while (__hip_atomic_load(&flag_dep[t], __ATOMIC_RELAXED,
                                 __HIP_MEMORY_SCOPE_AGENT) < NWG)
          __builtin_amdgcn_s_sleep(1);
      }
    }
    __syncthreads();
    __builtin_amdgcn_fence(__ATOMIC_ACQUIRE, "agent");  // inv L1/L2, all waves

    const u16* hread  = hbuf + (size_t)(t & 1) * (BB * HH);
    u16*       hwrite = hbuf + (size_t)((t + 1) & 1) * (BB * HH);

    f32x4 acc0 = {0.f, 0.f, 0.f, 0.f};
    f32x4 acc1 = {0.f, 0.f, 0.f, 0.f};

    // input contribution: x_t (B x KIN) @ Wih^T
    if (XF32) {
      const float* xp = (const float*)xin +
                        (size_t)arow * SS * KIN + (size_t)t * KIN + q * 8;
#pragma unroll
      for (int ks = 0; ks < KIN / 32; ++ks) {
        bf16x8 a = cvt8(xp + ks * 32);
        acc0 = __builtin_amdgcn_mfma_f32_16x16x32_bf16(a, wihA[ks], acc0, 0, 0, 0);
        acc1 = __builtin_amdgcn_mfma_f32_16x16x32_bf16(a, wihB[ks], acc1, 0, 0, 0);
      }
    } else {
      const u16* xp = (const u16*)xin +
                      (size_t)arow * SS * KIN + (size_t)t * KIN + q * 8;
#pragma unroll
      for (int ks = 0; ks < KIN / 32; ++ks) {
        bf16x8 a = ldfrag(xp + ks * 32);
        acc0 = __builtin_amdgcn_mfma_f32_16x16x32_bf16(a, wihA[ks], acc0, 0, 0, 0);
        acc1 = __builtin_amdgcn_mfma_f32_16x16x32_bf16(a, wihB[ks], acc1, 0, 0, 0);
      }
    }
    // recurrent contribution: h_t (B x 512) @ Whh^T  (h stored bf16)
    const u16* hp = hread + (size_t)arow * HH + q * 8;
#pragma unroll
    for (int ks = 0; ks < 16; ++ks) {
      bf16x8 a = ldfrag(hp + ks * 32);
      acc0 = __builtin_amdgcn_mfma_f32_16x16x32_bf16(a, whhA[ks], acc0, 0, 0, 0);
      acc1 = __builtin_amdgcn_mfma_f32_16x16x32_bf16(a, whhB[ks], acc1, 0, 0, 0);
    }

    // add biases, then swap f/o halves into low-column lanes via shfl_xor(8)
    float a0[4], a1[4], p0[4], p1[4];
#pragma unroll
    for (int r = 0; r < 4; ++r) { a0[r] = acc0[r] + bias0; a1[r] = acc1[r] + bias1; }
#pragma unroll
    for (int r = 0; r < 4; ++r) {
      p0[r] = __shfl_xor(a0[r], 8, 64);   // f pre-activations (for n16<8)
      p1[r] = __shfl_xor(a1[r], 8, 64);   // o pre-activations
    }

    if (n16 < 8) {
      const int hcol = g8 + n16;
#pragma unroll
      for (int r = 0; r < 4; ++r) {
        const int b = wv * 16 + q * 4 + r;
        float ig = sigm(a0[r]);
        float fg = sigm(p0[r]);
        float gg = tanh_f(a1[r]);
        float og = sigm(p1[r]);
        float cv = fg * cst[r] + ig * gg;
        cst[r] = cv;
        float hv = og * tanh_f(cv);
        u16 hb = f2bf(hv);
        hwrite[(size_t)b * HH + hcol] = hb;       // bf16 recurrent feedback
        if (LAYER == 0) {
          outB[((size_t)b * SS + t) * HH + hcol] = hb;      // bf16 out0 (ws)
        } else {
          outF[((size_t)b * SS + t) * HH + hcol] = hv;      // fp32 out1
        }
        if (t == SS - 1) {
          hn[(size_t)b * HH + hcol] = hv;                   // fp32 h_n
          cn[(size_t)b * HH + hcol] = cv;                   // fp32 c_n
        }
      }
    }

    __syncthreads();  // all waves' stores drained (vmcnt) before release
    if (tid == 0) {
      __hip_atomic_fetch_add(&flag_own[t], 1, __ATOMIC_RELEASE,
                             __HIP_MEMORY_SCOPE_AGENT);  // wbl2 + flag
    }
  }
}

__global__ __launch_bounds__(256, 1) void lstm_persist(
    const float* __restrict__ x,
    const float* __restrict__ Wih0, const float* __restrict__ Whh0,
    const float* __restrict__ bih0, const float* __restrict__ bhh0,
    const float* __restrict__ Wih1, const float* __restrict__ Whh1,
    const float* __restrict__ bih1, const float* __restrict__ bhh1,
    u16* out0, float* out1, float* hn, float* cn,
    u16* hbuf, int* flags)
{
  const int layer = blockIdx.x >> 6;
  if (layer == 0) {
    run_layer<256, 0, true>(x, Wih0, Whh0, bih0, bhh0,
                            nullptr, out0, hn, cn,
                            hbuf, flags, nullptr);
  } else {
    run_layer<512, 1, false>(out0, Wih1, Whh1, bih1, bhh1,
                             out1, nullptr,
                             hn + (size_t)BB * HH, cn + (size_t)BB * HH,
                             hbuf + 2 * (size_t)BB * HH, flags + SS, flags);
  }
}

extern "C" void kernel_launch(void* const* d_in, const int* in_sizes, int n_in,
                              void* d_out, int out_size, void* d_ws, size_t ws_size,
                              hipStream_t stream) {
  const float* x    = (const float*)d_in[0];
  const float* Wih0 = (const float*)d_in[1];
  const float* Whh0 = (const float*)d_in[2];
  const float* bih0 = (const float*)d_in[3];
  const float* bhh0 = (const float*)d_in[4];
  const float* Wih1 = (const float*)d_in[5];
  const float* Whh1 = (const float*)d_in[6];
  const float* bih1 = (const float*)d_in[7];
  const float* bhh1 = (const float*)d_in[8];

  float* out  = (float*)d_out;
  float* out1 = out;                                  // (64,1024,512) fp32
  float* hn   = out + (size_t)BB * SS * HH;           // (2,64,512) fp32
  float* cn   = hn + 2 * (size_t)BB * HH;             // (2,64,512) fp32

  char* ws = (char*)d_ws;
  const size_t out0_bytes = (size_t)BB * SS * HH * 2; // 67,108,864 (bf16 out0)
  const size_t hbuf_bytes = 4 * (size_t)BB * HH * 2;  // 262,144
  const size_t flag_bytes = 2 * (size_t)SS * 4;       // 8,192
  if (ws_size < out0_bytes + hbuf_bytes + flag_bytes) return;

  u16* out0  = (u16*)ws;
  u16* hbuf  = (u16*)(ws + out0_bytes);
  int* flags = (int*)(ws + out0_bytes + hbuf_bytes);

  // zero h ping-pong buffers (h0 = c0 = 0) and the arrival flags
  hipMemsetAsync(hbuf, 0, hbuf_bytes + flag_bytes, stream);

  lstm_persist<<<dim3(2 * NWG), dim3(256), 0, stream>>>(
      x, Wih0, Whh0, bih0, bhh0, Wih1, Whh1, bih1, bhh1,
      out0, out1, hn, cn, hbuf, flags);
}